// Round 11
// baseline (356.676 us; speedup 1.0000x reference)
//
#include <hip/hip_runtime.h>
#include <math.h>

// Problem constants (from reference)
#define HH   2560
#define ESZ  2048
#define BB   64
#define TT   32
#define INSZ 128
constexpr float ALPHA_C = 0.2f;   // dt_x / tau_x

typedef unsigned short ushort_t;
typedef __attribute__((ext_vector_type(8))) unsigned short u16x8;  // 8 bf16 = 4 VGPRs
typedef __attribute__((ext_vector_type(4))) float f32x4;           // MFMA acc

__device__ __forceinline__ float retanh_f(float v) { return tanhf(fmaxf(v, 0.f)); }
__device__ __forceinline__ ushort_t f2bf(float f) {   // RNE float->bf16
    unsigned u = __float_as_uint(f);
    return (ushort_t)((u + 0x7fffu + ((u >> 16) & 1u)) >> 16);
}

// Area geometry (kron structure). Rows of area a (E and I) share one sparse col set:
// E-cols of areas [a-1..a+1] (n_e), then I-cols of area a (128), then x-cols (area0).
__device__ __forceinline__ int area_ne(int a)  { return (a == 1 || a == 2) ? 1536 : 1024; }
__device__ __forceinline__ int area_elo(int a) { return (a > 0 ? a - 1 : 0) << 9; }

// ============ fused pack kernel (one dispatch) ============
// bid [0,2080): WF fragments (coalesced row-walk); [2080,3104): xF; [3104,3744): init.
// WF mapping: thread = (W-row h, col-chunk cc). Consecutive threads read consecutive
// 32B chunks ALONG row h (fully coalesced HBM reads), emit ONE 16B fragment store.
// Packed col space per region is 8-aligned, so a chunk never splits across slots.
__global__ __launch_bounds__(256) void pack_all(
    const float* __restrict__ Wrec, const float* __restrict__ Win,
    const float* __restrict__ x, const float* __restrict__ state0,
    ushort_t* __restrict__ WF, ushort_t* __restrict__ xF,
    float* __restrict__ stateT, ushort_t* __restrict__ act2)
{
    const int bid = blockIdx.x;
    if (bid < 2080) {
        int idx = bid * 256 + threadIdx.x;   // < 2560*208
        int h = idx / 208, cc = idx - h * 208;
        int ar, ridx;
        if (h < ESZ) { ar = h >> 9;         ridx = h & 511; }
        else         { ar = (h - ESZ) >> 7; ridx = 512 + ((h - ESZ) & 127); }
        int ne = area_ne(ar), elo = area_elo(ar);
        int nrec = ne + 128;
        int ntot = nrec + (ar == 0 ? 128 : 0);   // = 32*KC(ar): step kernel reads exactly this
        int p0 = cc * 8;
        if (p0 < ntot) {
            float vals[8];
            if (p0 < ne) {                       // E-cols: +|W|, diag zeroed
                int c0 = elo + p0;
                const float* src = Wrec + (size_t)h * HH + c0;
#pragma unroll
                for (int i = 0; i < 8; i++) {
                    float w = fabsf(src[i]);
                    vals[i] = (c0 + i == h) ? 0.f : w;
                }
            } else if (p0 < nrec) {              // I-cols: -|W|, diag zeroed
                int c0 = ESZ + (ar << 7) + (p0 - ne);
                const float* src = Wrec + (size_t)h * HH + c0;
#pragma unroll
                for (int i = 0; i < 8; i++) {
                    float w = -fabsf(src[i]);
                    vals[i] = (c0 + i == h) ? 0.f : w;
                }
            } else {                             // x-cols (area0): +|Win|
                const float* src = Win + (size_t)h * INSZ + (p0 - nrec);
#pragma unroll
                for (int i = 0; i < 8; i++) vals[i] = fabsf(src[i]);
            }
            int mt = ar * 40 + (ridx >> 4);
            int kc = p0 >> 5;
            int lane = (((p0 >> 3) & 3) << 4) + (ridx & 15);
            u16x8 o;
#pragma unroll
            for (int i = 0; i < 8; i++) o[i] = f2bf(vals[i]);
            *(u16x8*)(WF + ((size_t)(mt * 52 + kc) * 512 + lane * 8)) = o;
        }
    } else if (bid < 3104) {
        // xF[t*8192 + kc*2048 + nt*512 + lane*8 + j] = bf16 relu(x_t) fragment
        int idx = (bid - 2080) * 256 + threadIdx.x;   // < 32*4*4*512
        int j = idx & 7, l = (idx >> 3) & 63;
        int nt = (idx >> 9) & 3, kc = (idx >> 11) & 3, t = idx >> 13;
        int b = nt * 16 + (l & 15);
        int k = kc * 32 + ((l >> 4) << 3) + j;
        xF[idx] = f2bf(fmaxf(x[((size_t)t * BB + b) * INSZ + k], 0.f));
    } else {
        // state0 -> stateT (packed-row fp32) + compact act2[b][h] bf16 (coalesced)
        int idx = (bid - 3104) * 256 + threadIdx.x;   // < BB*HH, idx = b*HH + h
        int b = idx / HH, h = idx - b * HH;
        float s = state0[idx];
        int r = (h < ESZ) ? ((h >> 9) * 640 + (h & 511))
                          : (((h - ESZ) >> 7) * 640 + 512 + ((h - ESZ) & 127));
        stateT[r * BB + b] = s;
        act2[idx] = f2bf(retanh_f(s));
    }
}

// ============ one RNN step: bf16 MFMA GEMM, fully-unrolled K, compact act ============
// 640 blocks x 256 thr (4 waves). Block = (area, mt_local, nt): 16 rows x 16 batch,
// waves K-split 4. ALL af/bf loads issued upfront (<=26 dwordx4 in flight).
// B-fragments gathered straight from compact act2[b][h]: packed col p -> h is
// CONTIGUOUS within each 8-aligned region, so lane's 8 bf16 = one aligned 16B load
// at act2[b*HH + h0]. Epilogue: ONE coalesced bf16 store per output (no scatter,
// no 3x area duplication) -> minimal end-of-kernel drain before the next dispatch.
// bid encode: XCD=bid%8 pins area a to XCD pair {2a,2a+1}.
__global__ __launch_bounds__(256) void step10(
    const ushort_t* __restrict__ WF,
    const ushort_t* __restrict__ act_in,   // [b][h] bf16 compact
    ushort_t* __restrict__ act_out,        // [b][h] bf16 compact
    const ushort_t* __restrict__ xFt,      // this step's x fragments (area0 cols)
    const float* __restrict__ brec,
    float* __restrict__ stateT,            // [r][BB] fp32
    float* __restrict__ out_t)             // [BB][HH] fp32
{
    __shared__ float part[4 * 256];
    const int tid = threadIdx.x, lane = tid & 63, wv = tid >> 6;
    const int bid = blockIdx.x;
    const int area = (bid >> 1) & 3;
    const int nt   = ((bid >> 2) & 2) | (bid & 1);
    const int ml   = bid >> 4;            // mt_local 0..39
    const int mt   = area * 40 + ml;
    const int r0   = area * 640 + ml * 16;

    const int ne  = area_ne(area), elo = area_elo(area);
    const int ilo = ESZ + (area << 7);

    f32x4 acc0 = {0.f, 0.f, 0.f, 0.f}, acc1 = {0.f, 0.f, 0.f, 0.f};
    // kc = wv + 4*i ; af offset = kc*512
    const ushort_t* aptr = WF + ((size_t)mt * 52 + wv) * 512 + lane * 8;
    const ushort_t* a2   = act_in + (size_t)(nt * 16 + (lane & 15)) * HH;
    const int koff = (lane >> 4) << 3;
    const ushort_t* xptr = xFt + ((wv * 4) + nt) * 512 + lane * 8;   // area0, kc=36+wv

#define KLOOP(NIT, HASX)                                                     \
    {                                                                        \
        u16x8 af[NIT], bf[NIT];                                              \
        _Pragma("unroll")                                                    \
        for (int i = 0; i < (NIT); i++) {                                    \
            af[i] = *(const u16x8*)(aptr + (size_t)i * 2048);                \
            if ((HASX) && i == (NIT) - 1) {                                  \
                bf[i] = *(const u16x8*)xptr;                                 \
            } else {                                                         \
                int p0 = (wv + 4 * i) * 32 + koff;                           \
                int h0 = (p0 < ne) ? (elo + p0) : (ilo + (p0 - ne));         \
                bf[i] = *(const u16x8*)(a2 + h0);                            \
            }                                                                \
        }                                                                    \
        _Pragma("unroll")                                                    \
        for (int i = 0; i < (NIT); i++) {                                    \
            if (i & 1)                                                       \
                asm volatile("v_mfma_f32_16x16x32_bf16 %0, %1, %2, %0"       \
                             : "+v"(acc1) : "v"(af[i]), "v"(bf[i]));         \
            else                                                             \
                asm volatile("v_mfma_f32_16x16x32_bf16 %0, %1, %2, %0"       \
                             : "+v"(acc0) : "v"(af[i]), "v"(bf[i]));         \
        }                                                                    \
    }

    // KC per area: 40 / 52 / 52 / 36 (all %4==0); per-wave NIT = KC/4.
    // Area0: kc in [36,40) are x-chunks -> each wave's LAST iteration.
    if (area == 0)      KLOOP(10, true)
    else if (area == 3) KLOOP(9,  false)
    else                KLOOP(13, false)
#undef KLOOP

    // hazard gap: VALU read of MFMA result needs a few cycles
    asm volatile("s_nop 7\n\ts_nop 7" : "+v"(acc0), "+v"(acc1));

    // C/D layout: n = lane&15, m = (lane>>4)*4 + i   [m89-verified]
#pragma unroll
    for (int i = 0; i < 4; i++)
        part[wv * 256 + (lane & 15) * 16 + ((lane >> 4) << 2) + i] = acc0[i] + acc1[i];
    __syncthreads();

    {   // 256 outputs (16m x 16n), one per thread; mm fastest -> h-consecutive stores
        const int mm = tid & 15, nn = tid >> 4;
        float s = part[nn * 16 + mm] + part[256 + nn * 16 + mm]
                + part[512 + nn * 16 + mm] + part[768 + nn * 16 + mm];
        const int b = nt * 16 + nn;
        const int ridx = ml * 16 + mm;
        const int h = (ridx < 512) ? ((area << 9) + ridx)
                                   : (ESZ + (area << 7) + (ridx - 512));
        const int r = r0 + mm;
        float st = stateT[r * BB + b];
        float ns = st * (1.f - ALPHA_C) + ALPHA_C * (s + brec[h]);
        stateT[r * BB + b] = ns;
        float o = retanh_f(ns);
        out_t[(size_t)b * HH + h] = o;
        act_out[(size_t)b * HH + h] = f2bf(o);   // single coalesced bf16 store
    }
}

// ============ fallback (tiny ws): raw-W streaming path ============
__device__ __forceinline__ void area_params(int area, int& e_lo, int& n_e,
                                            int& i_lo, int& n_rec, int& n_tot) {
    e_lo = (area > 0 ? area - 1 : 0) << 9;
    int e_hi = ((area < 3 ? area + 1 : 3) + 1) << 9;
    n_e = e_hi - e_lo;
    i_lo = ESZ + (area << 7);
    n_rec = n_e + 128;
    n_tot = n_rec + (area == 0 ? INSZ : 0);
}
__device__ __forceinline__ int row_h(int area, int idx) {
    return (idx < 512) ? ((area << 9) + idx) : (ESZ + (area << 7) + (idx - 512));
}
__global__ __launch_bounds__(256) void init_state2(const float* __restrict__ state0,
                                                   float* __restrict__ stateT,
                                                   float* __restrict__ act0) {
    int idx = blockIdx.x * 256 + threadIdx.x;
    int b = idx / HH, h = idx - b * HH;
    float s = state0[idx];
    int r = (h < ESZ) ? ((h >> 9) * 640 + (h & 511))
                      : (((h - ESZ) >> 7) * 640 + 512 + ((h - ESZ) & 127));
    stateT[r * BB + b] = s;
    act0[((h >> 1) << 7) + b * 2 + (h & 1)] = retanh_f(s);
}
__global__ __launch_bounds__(1024, 4) void step_raw(
    const float* __restrict__ W, const float* __restrict__ Win,
    const float* __restrict__ brec, const float* __restrict__ x_t,
    const float* __restrict__ actIn, float* __restrict__ actOut,
    float* __restrict__ stateT, float* __restrict__ out_t)
{
    __shared__ float part[16 * 680];
    const int tid = threadIdx.x, lane = tid & 63, wv = tid >> 6;
    const int area = blockIdx.x >> 6;
    const int rb = (blockIdx.x & 63) * 10;
    int e_lo, n_e, i_lo, n_rec, n_tot;
    area_params(area, e_lo, n_e, i_lo, n_rec, n_tot);
    const int r0 = area * 640 + rb;
    const int C = n_tot >> 4;
    float2 acc[10];
#pragma unroll
    for (int j = 0; j < 10; j++) acc[j] = make_float2(0.f, 0.f);
    for (int c = wv; c < C; c += 16) {
        const int p0 = c << 4;
        float2 av[8];
        int cbase;
        if (p0 < n_rec) {
            cbase = (p0 < n_e) ? (e_lo + p0) : (i_lo + (p0 - n_e));
            const float* ap = actIn + ((cbase >> 1) << 7) + lane * 2;
#pragma unroll
            for (int i = 0; i < 8; i++) av[i] = *(const float2*)(ap + (i << 7));
        } else {
            cbase = -1;
            const int k0 = p0 - n_rec;
            const float4* xp = (const float4*)(x_t + lane * INSZ + k0);
#pragma unroll
            for (int q = 0; q < 4; q++) {
                float4 v = xp[q];
                av[2 * q]     = make_float2(fmaxf(v.x, 0.f), fmaxf(v.y, 0.f));
                av[2 * q + 1] = make_float2(fmaxf(v.z, 0.f), fmaxf(v.w, 0.f));
            }
        }
#pragma unroll
        for (int j = 0; j < 10; j++) {
            const int h = row_h(area, rb + j);
            const float sgn = (cbase >= 0 && p0 >= n_e) ? -1.f : 1.f;
            const float* wr = (cbase >= 0) ? (W + (size_t)h * HH + cbase)
                                           : (Win + (size_t)h * INSZ + (p0 - n_rec));
#pragma unroll
            for (int i = 0; i < 8; i++) {
                acc[j].x = fmaf(sgn * fabsf(wr[2 * i]),     av[i].x, acc[j].x);
                acc[j].y = fmaf(sgn * fabsf(wr[2 * i + 1]), av[i].y, acc[j].y);
            }
        }
    }
#pragma unroll
    for (int j = 0; j < 10; j++)
        part[wv * 680 + j * 68 + lane] = acc[j].x + acc[j].y;
    __syncthreads();
    int j = -1, b = 0;
    if (tid < 512)      { b = tid >> 3;      j = tid & 7; }
    else if (tid < 640) { int u = tid - 512; b = u >> 1;  j = 8 + (u & 1); }
    if (j >= 0) {
        const int h = row_h(area, rb + j);
        float s = 0.f;
#pragma unroll
        for (int w16 = 0; w16 < 16; w16++) s += part[w16 * 680 + j * 68 + b];
        float sgn = (h < ESZ) ? 1.f : -1.f;
        s -= sgn * fabsf(W[(size_t)h * HH + h]) * actIn[((h >> 1) << 7) + b * 2 + (h & 1)];
        const int r = r0 + j;
        float st = stateT[r * BB + b];
        float ns = st * (1.f - ALPHA_C) + ALPHA_C * (s + brec[h]);
        stateT[r * BB + b] = ns;
        float o = retanh_f(ns);
        out_t[(size_t)b * HH + h] = o;
        actOut[((h >> 1) << 7) + b * 2 + (h & 1)] = o;
    }
}

extern "C" void kernel_launch(void* const* d_in, const int* in_sizes, int n_in,
                              void* d_out, int out_size, void* d_ws, size_t ws_size,
                              hipStream_t stream) {
    const float* x      = (const float*)d_in[0];
    const float* W_in   = (const float*)d_in[1];
    const float* W_rec  = (const float*)d_in[2];
    const float* b_rec  = (const float*)d_in[3];
    const float* state0 = (const float*)d_in[4];
    float* out = (float*)d_out;

    const size_t WFn = (size_t)160 * 52 * 512;   // 4,259,840 bf16
    const size_t xFn = (size_t)TT * 8192;        //   262,144 bf16
    const size_t aCn = (size_t)BB * HH;          //   163,840 bf16 (compact act)
    const size_t need = (WFn + xFn + 2 * aCn) * 2 + (size_t)HH * BB * 4;

    if (ws_size >= need) {
        ushort_t* WF   = (ushort_t*)d_ws;
        ushort_t* xF   = WF + WFn;
        ushort_t* actA = xF + xFn;
        ushort_t* actB = actA + aCn;
        float* stateT  = (float*)(actB + aCn);

        pack_all<<<3744, 256, 0, stream>>>(W_rec, W_in, x, state0, WF, xF, stateT, actA);
        for (int t = 0; t < TT; t++) {
            ushort_t* ai = (t & 1) ? actB : actA;
            ushort_t* ao = (t & 1) ? actA : actB;
            step10<<<640, 256, 0, stream>>>(WF, ai, ao, xF + (size_t)t * 8192,
                                            b_rec, stateT, out + (size_t)t * BB * HH);
        }
    } else {
        float* ws = (float*)d_ws;
        const size_t bufElems = (size_t)HH * BB;
        float* stateT = ws;
        float* actA   = stateT + bufElems;
        float* actB   = actA + bufElems;
        init_state2<<<(BB * HH) / 256, 256, 0, stream>>>(state0, stateT, actA);
        for (int t = 0; t < TT; t++) {
            const float* ai = (t & 1) ? actB : actA;
            float* ao       = (t & 1) ? actA : actB;
            step_raw<<<256, 1024, 0, stream>>>(W_rec, W_in, b_rec,
                                               x + (size_t)t * BB * INSZ,
                                               ai, ao, stateT, out + (size_t)t * BB * HH);
        }
    }
}

// Round 12
// 277.182 us; speedup vs baseline: 1.2868x; 1.2868x over previous
//
#include <hip/hip_runtime.h>
#include <math.h>

// Problem constants (from reference)
#define HH   2560
#define ESZ  2048
#define BB   64
#define TT   32
#define INSZ 128
constexpr float ALPHA_C = 0.2f;   // dt_x / tau_x

typedef unsigned short ushort_t;
typedef __attribute__((ext_vector_type(8))) unsigned short u16x8;  // 8 bf16 = 4 VGPRs
typedef __attribute__((ext_vector_type(4))) float f32x4;           // MFMA acc

__device__ __forceinline__ float retanh_f(float v) { return tanhf(fmaxf(v, 0.f)); }
__device__ __forceinline__ ushort_t f2bf(float f) {   // RNE float->bf16
    unsigned u = __float_as_uint(f);
    return (ushort_t)((u + 0x7fffu + ((u >> 16) & 1u)) >> 16);
}

// Area geometry (kron structure). Rows of area a (E and I) share one sparse col set:
// E-cols of areas [a-1..a+1] (n_e), then I-cols of area a (128), then x-cols (area0).
__device__ __forceinline__ int area_ne(int a)  { return (a == 1 || a == 2) ? 1536 : 1024; }
__device__ __forceinline__ int area_elo(int a) { return (a > 0 ? a - 1 : 0) << 9; }

// scatter one act value into B-fragment slots of every area whose col-space has h.
// NOTE (R11 lesson): this 3x-duplicated fragment buffer is a READ-optimized layout —
// consumer loads are 1KB-contiguous per wave. Compacting it (R11) made the consumer
// gather 4x less coalesced and cost +2.5us/step: reads are on the critical path,
// writes drain in parallel with the kernel tail. Keep the scatter.
__device__ __forceinline__ void act_store(ushort_t* actF, int a, int p, int b, ushort_t v) {
    int kc = p >> 5, kk = p & 31;
    int lane = ((kk >> 3) << 4) + (b & 15);
    actF[(((a * 52 + kc) << 2) + (b >> 4)) * 512 + lane * 8 + (kk & 7)] = v;
}
__device__ __forceinline__ void scatter_act(ushort_t* actF, int h, int b, ushort_t v) {
    if (h < ESZ) {
        int ae = h >> 9;
        int alo = ae > 0 ? ae - 1 : 0, ahi = ae < 3 ? ae + 1 : 3;
        for (int a = alo; a <= ahi; a++) act_store(actF, a, h - area_elo(a), b, v);
    } else {
        int ai = (h - ESZ) >> 7;
        act_store(actF, ai, area_ne(ai) + (h - (ESZ + (ai << 7))), b, v);
    }
}

// ============ fused pack kernel (one dispatch) ============
// bid [0,2080): WF fragments (coalesced row-walk); [2080,3104): xF; [3104,3744): init.
__global__ __launch_bounds__(256) void pack_all(
    const float* __restrict__ Wrec, const float* __restrict__ Win,
    const float* __restrict__ x, const float* __restrict__ state0,
    ushort_t* __restrict__ WF, ushort_t* __restrict__ xF,
    float* __restrict__ stateT, ushort_t* __restrict__ actF)
{
    const int bid = blockIdx.x;
    if (bid < 2080) {
        int idx = bid * 256 + threadIdx.x;   // < 2560*208
        int h = idx / 208, cc = idx - h * 208;
        int ar, ridx;
        if (h < ESZ) { ar = h >> 9;         ridx = h & 511; }
        else         { ar = (h - ESZ) >> 7; ridx = 512 + ((h - ESZ) & 127); }
        int ne = area_ne(ar), elo = area_elo(ar);
        int nrec = ne + 128;
        int ntot = nrec + (ar == 0 ? 128 : 0);   // = 32*KC(ar): step9 reads exactly this
        int p0 = cc * 8;
        if (p0 < ntot) {
            float vals[8];
            if (p0 < ne) {                       // E-cols: +|W|, diag zeroed
                int c0 = elo + p0;
                const float* src = Wrec + (size_t)h * HH + c0;
#pragma unroll
                for (int i = 0; i < 8; i++) {
                    float w = fabsf(src[i]);
                    vals[i] = (c0 + i == h) ? 0.f : w;
                }
            } else if (p0 < nrec) {              // I-cols: -|W|, diag zeroed
                int c0 = ESZ + (ar << 7) + (p0 - ne);
                const float* src = Wrec + (size_t)h * HH + c0;
#pragma unroll
                for (int i = 0; i < 8; i++) {
                    float w = -fabsf(src[i]);
                    vals[i] = (c0 + i == h) ? 0.f : w;
                }
            } else {                             // x-cols (area0): +|Win|
                const float* src = Win + (size_t)h * INSZ + (p0 - nrec);
#pragma unroll
                for (int i = 0; i < 8; i++) vals[i] = fabsf(src[i]);
            }
            int mt = ar * 40 + (ridx >> 4);
            int kc = p0 >> 5;
            int lane = (((p0 >> 3) & 3) << 4) + (ridx & 15);
            u16x8 o;
#pragma unroll
            for (int i = 0; i < 8; i++) o[i] = f2bf(vals[i]);
            *(u16x8*)(WF + ((size_t)(mt * 52 + kc) * 512 + lane * 8)) = o;
        }
    } else if (bid < 3104) {
        // xF[t*8192 + kc*2048 + nt*512 + lane*8 + j] = bf16 relu(x_t) fragment
        int idx = (bid - 2080) * 256 + threadIdx.x;   // < 32*4*4*512
        int j = idx & 7, l = (idx >> 3) & 63;
        int nt = (idx >> 9) & 3, kc = (idx >> 11) & 3, t = idx >> 13;
        int b = nt * 16 + (l & 15);
        int k = kc * 32 + ((l >> 4) << 3) + j;
        xF[idx] = f2bf(fmaxf(x[((size_t)t * BB + b) * INSZ + k], 0.f));
    } else {
        // state0 -> stateT (packed-row fp32) + initial act fragments
        int idx = (bid - 3104) * 256 + threadIdx.x;   // < BB*HH
        int b = idx / HH, h = idx - b * HH;
        float s = state0[idx];
        int r = (h < ESZ) ? ((h >> 9) * 640 + (h & 511))
                          : (((h - ESZ) >> 7) * 640 + 512 + ((h - ESZ) & 127));
        stateT[r * BB + b] = s;
        scatter_act(actF, h, b, f2bf(retanh_f(s)));
    }
}

// ============ one RNN step: bf16 MFMA GEMM, fully-unrolled K ============
// 640 blocks x 256 thr (4 waves). Block = (area, mt_local, nt): 16 rows x 16 batch,
// waves K-split 4. ALL af/bf loads issued upfront (<=26 dwordx4 in flight).
// Dual accumulators (even/odd i) halve the serial MFMA dependency depth (13 -> 7).
// bid encode: XCD=bid%8 pins area a to XCD pair {2a,2a+1}.
__global__ __launch_bounds__(256) void step9(
    const ushort_t* __restrict__ WF,
    const ushort_t* __restrict__ actF_in,
    ushort_t* __restrict__ actF_out,
    const ushort_t* __restrict__ xFt,     // this step's x fragments (area0 cols)
    const float* __restrict__ brec,
    float* __restrict__ stateT,           // [r][BB] fp32
    float* __restrict__ out_t)            // [BB][HH] fp32
{
    __shared__ float part[4 * 256];
    const int tid = threadIdx.x, lane = tid & 63, wv = tid >> 6;
    const int bid = blockIdx.x;
    const int area = (bid >> 1) & 3;
    const int nt   = ((bid >> 2) & 2) | (bid & 1);
    const int ml   = bid >> 4;            // mt_local 0..39
    const int mt   = area * 40 + ml;
    const int r0   = area * 640 + ml * 16;

    f32x4 acc0 = {0.f, 0.f, 0.f, 0.f}, acc1 = {0.f, 0.f, 0.f, 0.f};
    // kc = wv + 4*i ; af offset = kc*512 ; bf offset = ((area*52+kc)*4+nt)*512
    const ushort_t* aptr = WF + ((size_t)mt * 52 + wv) * 512 + lane * 8;
    const ushort_t* bptr = actF_in + (((size_t)area * 52 + wv) * 4 + nt) * 512 + lane * 8;
    const ushort_t* xptr = xFt + ((wv * 4) + nt) * 512 + lane * 8;   // area0, kc=36+wv

#define KLOOP(NIT, HASX)                                                     \
    {                                                                        \
        u16x8 af[NIT], bf[NIT];                                              \
        _Pragma("unroll")                                                    \
        for (int i = 0; i < (NIT); i++) {                                    \
            af[i] = *(const u16x8*)(aptr + (size_t)i * 2048);                \
            bf[i] = ((HASX) && i == (NIT) - 1)                               \
                        ? *(const u16x8*)xptr                                \
                        : *(const u16x8*)(bptr + (size_t)i * 8192);          \
        }                                                                    \
        _Pragma("unroll")                                                    \
        for (int i = 0; i < (NIT); i++) {                                    \
            if (i & 1)                                                       \
                asm volatile("v_mfma_f32_16x16x32_bf16 %0, %1, %2, %0"       \
                             : "+v"(acc1) : "v"(af[i]), "v"(bf[i]));         \
            else                                                             \
                asm volatile("v_mfma_f32_16x16x32_bf16 %0, %1, %2, %0"       \
                             : "+v"(acc0) : "v"(af[i]), "v"(bf[i]));         \
        }                                                                    \
    }

    // KC per area: 40 / 52 / 52 / 36 (all %4==0); per-wave NIT = KC/4.
    // Area0: kc in [36,40) are x-chunks -> each wave's LAST iteration.
    if (area == 0)      KLOOP(10, true)
    else if (area == 3) KLOOP(9,  false)
    else                KLOOP(13, false)
#undef KLOOP

    // hazard gap: VALU read of MFMA result needs a few cycles
    asm volatile("s_nop 7\n\ts_nop 7" : "+v"(acc0), "+v"(acc1));

    // C/D layout: n = lane&15, m = (lane>>4)*4 + i   [m89-verified]
#pragma unroll
    for (int i = 0; i < 4; i++)
        part[wv * 256 + (lane & 15) * 16 + ((lane >> 4) << 2) + i] = acc0[i] + acc1[i];
    __syncthreads();

    {   // 256 outputs (16m x 16n), one per thread; mm fastest -> h-consecutive stores
        const int mm = tid & 15, nn = tid >> 4;
        float s = part[nn * 16 + mm] + part[256 + nn * 16 + mm]
                + part[512 + nn * 16 + mm] + part[768 + nn * 16 + mm];
        const int b = nt * 16 + nn;
        const int ridx = ml * 16 + mm;
        const int h = (ridx < 512) ? ((area << 9) + ridx)
                                   : (ESZ + (area << 7) + (ridx - 512));
        const int r = r0 + mm;
        float st = stateT[r * BB + b];
        float ns = st * (1.f - ALPHA_C) + ALPHA_C * (s + brec[h]);
        stateT[r * BB + b] = ns;
        float o = retanh_f(ns);
        out_t[(size_t)b * HH + h] = o;
        scatter_act(actF_out, h, b, f2bf(o));
    }
}

// ============ fallback (tiny ws): raw-W streaming path ============
__device__ __forceinline__ void area_params(int area, int& e_lo, int& n_e,
                                            int& i_lo, int& n_rec, int& n_tot) {
    e_lo = (area > 0 ? area - 1 : 0) << 9;
    int e_hi = ((area < 3 ? area + 1 : 3) + 1) << 9;
    n_e = e_hi - e_lo;
    i_lo = ESZ + (area << 7);
    n_rec = n_e + 128;
    n_tot = n_rec + (area == 0 ? INSZ : 0);
}
__device__ __forceinline__ int row_h(int area, int idx) {
    return (idx < 512) ? ((area << 9) + idx) : (ESZ + (area << 7) + (idx - 512));
}
__global__ __launch_bounds__(256) void init_state2(const float* __restrict__ state0,
                                                   float* __restrict__ stateT,
                                                   float* __restrict__ act0) {
    int idx = blockIdx.x * 256 + threadIdx.x;
    int b = idx / HH, h = idx - b * HH;
    float s = state0[idx];
    int r = (h < ESZ) ? ((h >> 9) * 640 + (h & 511))
                      : (((h - ESZ) >> 7) * 640 + 512 + ((h - ESZ) & 127));
    stateT[r * BB + b] = s;
    act0[((h >> 1) << 7) + b * 2 + (h & 1)] = retanh_f(s);
}
__global__ __launch_bounds__(1024, 4) void step_raw(
    const float* __restrict__ W, const float* __restrict__ Win,
    const float* __restrict__ brec, const float* __restrict__ x_t,
    const float* __restrict__ actIn, float* __restrict__ actOut,
    float* __restrict__ stateT, float* __restrict__ out_t)
{
    __shared__ float part[16 * 680];
    const int tid = threadIdx.x, lane = tid & 63, wv = tid >> 6;
    const int area = blockIdx.x >> 6;
    const int rb = (blockIdx.x & 63) * 10;
    int e_lo, n_e, i_lo, n_rec, n_tot;
    area_params(area, e_lo, n_e, i_lo, n_rec, n_tot);
    const int r0 = area * 640 + rb;
    const int C = n_tot >> 4;
    float2 acc[10];
#pragma unroll
    for (int j = 0; j < 10; j++) acc[j] = make_float2(0.f, 0.f);
    for (int c = wv; c < C; c += 16) {
        const int p0 = c << 4;
        float2 av[8];
        int cbase;
        if (p0 < n_rec) {
            cbase = (p0 < n_e) ? (e_lo + p0) : (i_lo + (p0 - n_e));
            const float* ap = actIn + ((cbase >> 1) << 7) + lane * 2;
#pragma unroll
            for (int i = 0; i < 8; i++) av[i] = *(const float2*)(ap + (i << 7));
        } else {
            cbase = -1;
            const int k0 = p0 - n_rec;
            const float4* xp = (const float4*)(x_t + lane * INSZ + k0);
#pragma unroll
            for (int q = 0; q < 4; q++) {
                float4 v = xp[q];
                av[2 * q]     = make_float2(fmaxf(v.x, 0.f), fmaxf(v.y, 0.f));
                av[2 * q + 1] = make_float2(fmaxf(v.z, 0.f), fmaxf(v.w, 0.f));
            }
        }
#pragma unroll
        for (int j = 0; j < 10; j++) {
            const int h = row_h(area, rb + j);
            const float sgn = (cbase >= 0 && p0 >= n_e) ? -1.f : 1.f;
            const float* wr = (cbase >= 0) ? (W + (size_t)h * HH + cbase)
                                           : (Win + (size_t)h * INSZ + (p0 - n_rec));
#pragma unroll
            for (int i = 0; i < 8; i++) {
                acc[j].x = fmaf(sgn * fabsf(wr[2 * i]),     av[i].x, acc[j].x);
                acc[j].y = fmaf(sgn * fabsf(wr[2 * i + 1]), av[i].y, acc[j].y);
            }
        }
    }
#pragma unroll
    for (int j = 0; j < 10; j++)
        part[wv * 680 + j * 68 + lane] = acc[j].x + acc[j].y;
    __syncthreads();
    int j = -1, b = 0;
    if (tid < 512)      { b = tid >> 3;      j = tid & 7; }
    else if (tid < 640) { int u = tid - 512; b = u >> 1;  j = 8 + (u & 1); }
    if (j >= 0) {
        const int h = row_h(area, rb + j);
        float s = 0.f;
#pragma unroll
        for (int w16 = 0; w16 < 16; w16++) s += part[w16 * 680 + j * 68 + b];
        float sgn = (h < ESZ) ? 1.f : -1.f;
        s -= sgn * fabsf(W[(size_t)h * HH + h]) * actIn[((h >> 1) << 7) + b * 2 + (h & 1)];
        const int r = r0 + j;
        float st = stateT[r * BB + b];
        float ns = st * (1.f - ALPHA_C) + ALPHA_C * (s + brec[h]);
        stateT[r * BB + b] = ns;
        float o = retanh_f(ns);
        out_t[(size_t)b * HH + h] = o;
        actOut[((h >> 1) << 7) + b * 2 + (h & 1)] = o;
    }
}

extern "C" void kernel_launch(void* const* d_in, const int* in_sizes, int n_in,
                              void* d_out, int out_size, void* d_ws, size_t ws_size,
                              hipStream_t stream) {
    const float* x      = (const float*)d_in[0];
    const float* W_in   = (const float*)d_in[1];
    const float* W_rec  = (const float*)d_in[2];
    const float* b_rec  = (const float*)d_in[3];
    const float* state0 = (const float*)d_in[4];
    float* out = (float*)d_out;

    const size_t WFn = (size_t)160 * 52 * 512;   // 4,259,840 bf16
    const size_t xFn = (size_t)TT * 8192;        //   262,144 bf16
    const size_t aFn = (size_t)4 * 52 * 4 * 512; //   425,984 bf16
    const size_t need = (WFn + xFn + 2 * aFn) * 2 + (size_t)HH * BB * 4;

    if (ws_size >= need) {
        ushort_t* WF   = (ushort_t*)d_ws;
        ushort_t* xF   = WF + WFn;
        ushort_t* actA = xF + xFn;
        ushort_t* actB = actA + aFn;
        float* stateT  = (float*)(actB + aFn);

        pack_all<<<3744, 256, 0, stream>>>(W_rec, W_in, x, state0, WF, xF, stateT, actA);
        for (int t = 0; t < TT; t++) {
            ushort_t* ai = (t & 1) ? actB : actA;
            ushort_t* ao = (t & 1) ? actA : actB;
            step9<<<640, 256, 0, stream>>>(WF, ai, ao, xF + (size_t)t * 8192,
                                           b_rec, stateT, out + (size_t)t * BB * HH);
        }
    } else {
        float* ws = (float*)d_ws;
        const size_t bufElems = (size_t)HH * BB;
        float* stateT = ws;
        float* actA   = stateT + bufElems;
        float* actB   = actA + bufElems;
        init_state2<<<(BB * HH) / 256, 256, 0, stream>>>(state0, stateT, actA);
        for (int t = 0; t < TT; t++) {
            const float* ai = (t & 1) ? actB : actA;
            float* ao       = (t & 1) ? actA : actB;
            step_raw<<<256, 1024, 0, stream>>>(W_rec, W_in, b_rec,
                                               x + (size_t)t * BB * INSZ,
                                               ai, ao, stateT, out + (size_t)t * BB * HH);
        }
    }
}